// Round 1
// baseline (473.890 us; speedup 1.0000x reference)
//
#include <hip/hip_runtime.h>
#include <cstdint>

#define IN_CH 128
#define HID_CH 128
#define OUT_CH 64

// ---------------------------------------------------------------------------
// Edge-index layout detection: reference uses int64; harness doc says int32.
// If buffer is little-endian int64 with values < 2^31, every odd 32-bit word
// of the first 8 entries is 0. Random int32 src values make that ~impossible.
// ---------------------------------------------------------------------------
__global__ void detect_kernel(const int* __restrict__ edges32, int* __restrict__ flag) {
    if (threadIdx.x == 0 && blockIdx.x == 0) {
        int is64 = 1;
#pragma unroll
        for (int k = 1; k < 16; k += 2)
            if (edges32[k] != 0) is64 = 0;
        *flag = is64;
    }
}

__device__ __forceinline__ int edge_at(const void* edges, int is64, int idx) {
    if (is64) return (int)((const long long*)edges)[idx];
    return ((const int*)edges)[idx];
}

__global__ void count_kernel(const void* __restrict__ edges, const int* __restrict__ flag,
                             int* __restrict__ deg, int E) {
    int e = blockIdx.x * blockDim.x + threadIdx.x;
    if (e >= E) return;
    int is64 = *flag;
    int d = edge_at(edges, is64, E + e);
    atomicAdd(&deg[d], 1);
}

__global__ void dinv_kernel(const int* __restrict__ deg, float* __restrict__ dinv, int n) {
    int i = blockIdx.x * blockDim.x + threadIdx.x;
    if (i < n) dinv[i] = rsqrtf((float)(deg[i] + 1));  // +1 = self-loop
}

// Exclusive prefix sum of deg -> row_ptr[0..n], single block of 1024 threads.
// Wave-level shfl scan (no syncs) + serial scan of 16 wave sums.
__global__ __launch_bounds__(1024) void scan_kernel(const int* __restrict__ deg,
                                                    int* __restrict__ row_ptr, int n) {
    __shared__ int wsum[16];
    __shared__ int s_carry, s_total;
    int tid = threadIdx.x, lane = tid & 63, wid = tid >> 6;
    if (tid == 0) s_carry = 0;
    __syncthreads();
    for (int base = 0; base < n; base += 1024) {
        int i = base + tid;
        int v = (i < n) ? deg[i] : 0;
        int incl = v;
#pragma unroll
        for (int off = 1; off < 64; off <<= 1) {
            int t = __shfl_up(incl, off);
            if (lane >= off) incl += t;
        }
        if (lane == 63) wsum[wid] = incl;
        __syncthreads();
        if (tid == 0) {
            int run = 0;
#pragma unroll
            for (int w = 0; w < 16; w++) { int t = wsum[w]; wsum[w] = run; run += t; }
            s_total = run;
        }
        __syncthreads();
        if (i < n) row_ptr[i] = s_carry + wsum[wid] + (incl - v);
        __syncthreads();
        if (tid == 0) s_carry += s_total;
        __syncthreads();
    }
    if (threadIdx.x == 0) row_ptr[n] = s_carry;
}

__global__ void fill_kernel(const void* __restrict__ edges, const int* __restrict__ flag,
                            const int* __restrict__ row_ptr, int* __restrict__ fill,
                            int* __restrict__ col, int E) {
    int e = blockIdx.x * blockDim.x + threadIdx.x;
    if (e >= E) return;
    int is64 = *flag;
    int s = edge_at(edges, is64, e);
    int d = edge_at(edges, is64, E + e);
    int pos = row_ptr[d] + atomicAdd(&fill[d], 1);
    col[pos] = s;
}

// ---------------------------------------------------------------------------
// y[i][:] = (H[i][:] @ W) * dinv[i].  FIN fixed at 128. W staged in LDS.
// Block = 256 threads; thread computes a 4-node x 4-col microtile.
// FOUT=128: 32 nodes/block, 64 KB LDS. FOUT=64: 64 nodes/block, 32 KB LDS.
// A-rows read from global as half-wave-broadcast float4 (each element read
// exactly once per owning wave, so no LDS staging needed for A).
// ---------------------------------------------------------------------------
template <int FOUT>
__global__ __launch_bounds__(256) void gemm_scale(const float* __restrict__ H,
                                                  const float* __restrict__ W,
                                                  const float* __restrict__ dinv,
                                                  float* __restrict__ Y, int n) {
    constexpr int FIN = 128;
    constexpr int COLG = FOUT / 4;     // 4-col groups
    constexpr int ROWG = 256 / COLG;   // row groups
    constexpr int NODES = ROWG * 4;    // nodes per block
    __shared__ float Wlds[FIN * FOUT];
    int tid = threadIdx.x;
    for (int idx = tid * 4; idx < FIN * FOUT; idx += 1024) {
        *(float4*)&Wlds[idx] = *(const float4*)&W[idx];
    }
    __syncthreads();
    int r0 = blockIdx.x * NODES;
    int cx = tid % COLG;
    int ry = tid / COLG;
    int nodes[4];
#pragma unroll
    for (int nn = 0; nn < 4; nn++) {
        int node = r0 + ry * 4 + nn;
        nodes[nn] = (node < n) ? node : (n - 1);  // clamp; store is guarded
    }
    float acc[4][4] = {};
    for (int k = 0; k < FIN; k += 4) {
        float4 b0 = *(const float4*)&Wlds[(k + 0) * FOUT + 4 * cx];
        float4 b1 = *(const float4*)&Wlds[(k + 1) * FOUT + 4 * cx];
        float4 b2 = *(const float4*)&Wlds[(k + 2) * FOUT + 4 * cx];
        float4 b3 = *(const float4*)&Wlds[(k + 3) * FOUT + 4 * cx];
#pragma unroll
        for (int nn = 0; nn < 4; nn++) {
            float4 a = *(const float4*)&H[nodes[nn] * FIN + k];
            acc[nn][0] += a.x * b0.x + a.y * b1.x + a.z * b2.x + a.w * b3.x;
            acc[nn][1] += a.x * b0.y + a.y * b1.y + a.z * b2.y + a.w * b3.y;
            acc[nn][2] += a.x * b0.z + a.y * b1.z + a.z * b2.z + a.w * b3.z;
            acc[nn][3] += a.x * b0.w + a.y * b1.w + a.z * b2.w + a.w * b3.w;
        }
    }
#pragma unroll
    for (int nn = 0; nn < 4; nn++) {
        int node = r0 + ry * 4 + nn;
        if (node < n) {
            float di = dinv[node];
            float4 o;
            o.x = acc[nn][0] * di;
            o.y = acc[nn][1] * di;
            o.z = acc[nn][2] * di;
            o.w = acc[nn][3] * di;
            *(float4*)&Y[node * FOUT + 4 * cx] = o;
        }
    }
}

// ---------------------------------------------------------------------------
// out[i] = maybe_relu( dinv[i] * (y[i] + sum_{e: dst=i} y[col[e]]) + bias )
// One wave per node; lane covers CH/64 channels. Neighbor ids fetched in
// 64-wide batches by the wave, broadcast via shfl; 4 independent accumulator
// chains so the gather loads overlap.
// ---------------------------------------------------------------------------
template <int CH, bool RELU>
__global__ __launch_bounds__(256) void aggregate_kernel(
    const float* __restrict__ Y, const int* __restrict__ row_ptr,
    const int* __restrict__ col, const float* __restrict__ dinv,
    const float* __restrict__ bias, float* __restrict__ out, int n) {
    int w = blockIdx.x * 4 + (threadIdx.x >> 6);
    int lane = threadIdx.x & 63;
    if (w >= n) return;
    constexpr int V = CH / 64;  // 2 (128ch) or 1 (64ch)
    float a0x = 0, a0y = 0, a1x = 0, a1y = 0, a2x = 0, a2y = 0, a3x = 0, a3y = 0;
    if (V == 2) {
        float2 s = *(const float2*)&Y[w * CH + lane * 2];
        a0x = s.x; a0y = s.y;
    } else {
        a0x = Y[w * CH + lane];
    }
    int start = row_ptr[w], end = row_ptr[w + 1];
    for (int base = start; base < end; base += 64) {
        int cnt = min(64, end - base);
        int sv = (base + lane < end) ? col[base + lane] : 0;
        int j = 0;
        for (; j + 4 <= cnt; j += 4) {
            int s0 = __shfl(sv, j + 0);
            int s1 = __shfl(sv, j + 1);
            int s2 = __shfl(sv, j + 2);
            int s3 = __shfl(sv, j + 3);
            if (V == 2) {
                float2 v0 = *(const float2*)&Y[s0 * CH + lane * 2];
                float2 v1 = *(const float2*)&Y[s1 * CH + lane * 2];
                float2 v2 = *(const float2*)&Y[s2 * CH + lane * 2];
                float2 v3 = *(const float2*)&Y[s3 * CH + lane * 2];
                a0x += v0.x; a0y += v0.y;
                a1x += v1.x; a1y += v1.y;
                a2x += v2.x; a2y += v2.y;
                a3x += v3.x; a3y += v3.y;
            } else {
                a0x += Y[s0 * CH + lane];
                a1x += Y[s1 * CH + lane];
                a2x += Y[s2 * CH + lane];
                a3x += Y[s3 * CH + lane];
            }
        }
        for (; j < cnt; j++) {
            int s = __shfl(sv, j);
            if (V == 2) {
                float2 v = *(const float2*)&Y[s * CH + lane * 2];
                a0x += v.x; a0y += v.y;
            } else {
                a0x += Y[s * CH + lane];
            }
        }
    }
    float di = dinv[w];
    if (V == 2) {
        float ox = (a0x + a1x + a2x + a3x) * di + bias[lane * 2];
        float oy = (a0y + a1y + a2y + a3y) * di + bias[lane * 2 + 1];
        if (RELU) { ox = fmaxf(ox, 0.f); oy = fmaxf(oy, 0.f); }
        float2 o; o.x = ox; o.y = oy;
        *(float2*)&out[w * CH + lane * 2] = o;
    } else {
        float ox = (a0x + a1x + a2x + a3x) * di + bias[lane];
        if (RELU) ox = fmaxf(ox, 0.f);
        out[w * CH + lane] = ox;
    }
}

extern "C" void kernel_launch(void* const* d_in, const int* in_sizes, int n_in,
                              void* d_out, int out_size, void* d_ws, size_t ws_size,
                              hipStream_t stream) {
    const float* x  = (const float*)d_in[0];
    const void*  ei = d_in[1];
    const float* W1 = (const float*)d_in[2];
    const float* b1 = (const float*)d_in[3];
    const float* W2 = (const float*)d_in[4];
    const float* b2 = (const float*)d_in[5];
    const float* W3 = (const float*)d_in[6];
    const float* b3 = (const float*)d_in[7];
    int n = in_sizes[0] / IN_CH;   // 50000
    int E = in_sizes[1] / 2;       // 800000

    // workspace carve (256B-aligned), total ~55 MB
    char* p = (char*)d_ws;
    auto carve = [&](size_t bytes) {
        char* r = p;
        p += (bytes + 255) & ~(size_t)255;
        return r;
    };
    int*   flag    = (int*)carve(4);
    int*   deg     = (int*)carve((size_t)n * 4);       // also reused as fill counters
    float* dinv    = (float*)carve((size_t)n * 4);
    int*   row_ptr = (int*)carve((size_t)(n + 1) * 4);
    int*   col     = (int*)carve((size_t)E * 4);
    float* y       = (float*)carve((size_t)n * HID_CH * 4);
    float* h       = (float*)carve((size_t)n * HID_CH * 4);

    const int tpb = 256;
    int eb = (E + tpb - 1) / tpb;
    int nb = (n + tpb - 1) / tpb;

    // ---- CSR + norm build (once per call, reused by all 3 layers) ----
    hipMemsetAsync(deg, 0, (size_t)n * 4, stream);
    detect_kernel<<<1, 64, 0, stream>>>((const int*)ei, flag);
    count_kernel<<<eb, tpb, 0, stream>>>(ei, flag, deg, E);
    dinv_kernel<<<nb, tpb, 0, stream>>>(deg, dinv, n);
    scan_kernel<<<1, 1024, 0, stream>>>(deg, row_ptr, n);
    hipMemsetAsync(deg, 0, (size_t)n * 4, stream);  // now fill counters
    fill_kernel<<<eb, tpb, 0, stream>>>(ei, flag, row_ptr, deg, col, E);

    int gb128 = (n + 31) / 32;
    int gb64  = (n + 63) / 64;
    int ab    = (n + 3) / 4;

    // ---- layer 1: x @ W1 -> relu(agg) ----
    gemm_scale<128><<<gb128, 256, 0, stream>>>(x, W1, dinv, y, n);
    aggregate_kernel<128, true><<<ab, 256, 0, stream>>>(y, row_ptr, col, dinv, b1, h, n);
    // ---- layer 2 ----
    gemm_scale<128><<<gb128, 256, 0, stream>>>(h, W2, dinv, y, n);
    aggregate_kernel<128, true><<<ab, 256, 0, stream>>>(y, row_ptr, col, dinv, b2, h, n);
    // ---- layer 3 (no relu, 64 ch) ----
    gemm_scale<64><<<gb64, 256, 0, stream>>>(h, W3, dinv, y, n);
    aggregate_kernel<64, false><<<ab, 256, 0, stream>>>(y, row_ptr, col, dinv, b3,
                                                        (float*)d_out, n);
}

// Round 2
// 362.142 us; speedup vs baseline: 1.3086x; 1.3086x over previous
//
#include <hip/hip_runtime.h>
#include <cstdint>

#define IN_CH 128
#define HID_CH 128
#define OUT_CH 64

// ---------------------------------------------------------------------------
// int64-vs-int32 edge layout detection, inlined (no separate kernel): if the
// buffer is little-endian int64 with values in [0, 2^31), the odd 32-bit words
// of the first 4 entries are all 0. For random int32 node ids the probability
// of that is ~(1/N)^4 ~ 0.
// ---------------------------------------------------------------------------
__device__ __forceinline__ int detect64(const int* __restrict__ e32) {
    return (e32[1] | e32[3] | e32[5] | e32[7]) == 0;
}

__device__ __forceinline__ int edge_at(const void* edges, int is64, int idx) {
    if (is64) return (int)((const long long*)edges)[idx];
    return ((const int*)edges)[idx];
}

__global__ void count_kernel(const void* __restrict__ edges, int* __restrict__ deg, int E) {
    int e = blockIdx.x * blockDim.x + threadIdx.x;
    if (e >= E) return;
    int is64 = detect64((const int*)edges);
    int d = edge_at(edges, is64, E + e);
    atomicAdd(&deg[d], 1);
}

// ---- 3-phase parallel exclusive scan of deg -> row_ptr, plus dinv fused ----
__global__ __launch_bounds__(1024) void scan_block_kernel(
    const int* __restrict__ deg, int* __restrict__ row_ptr,
    int* __restrict__ bsum, float* __restrict__ dinv, int n) {
    __shared__ int wsum[16];
    int tid = threadIdx.x, lane = tid & 63, wid = tid >> 6;
    int i = blockIdx.x * 1024 + tid;
    int v = (i < n) ? deg[i] : 0;
    if (i < n) dinv[i] = rsqrtf((float)(v + 1));  // +1 = self-loop
    int incl = v;
#pragma unroll
    for (int off = 1; off < 64; off <<= 1) {
        int t = __shfl_up(incl, off);
        if (lane >= off) incl += t;
    }
    if (lane == 63) wsum[wid] = incl;
    __syncthreads();
    if (wid == 0) {
        int s = (lane < 16) ? wsum[lane] : 0;
#pragma unroll
        for (int off = 1; off < 16; off <<= 1) {
            int t = __shfl_up(s, off);
            if (lane >= off) s += t;
        }
        if (lane < 16) wsum[lane] = s;  // inclusive wave sums
    }
    __syncthreads();
    int woff = (wid > 0) ? wsum[wid - 1] : 0;
    if (i < n) row_ptr[i] = woff + (incl - v);
    if (tid == 1023) bsum[blockIdx.x] = wsum[15];
}

__global__ void scan_totals_kernel(const int* __restrict__ bsum, int* __restrict__ boff,
                                   int* __restrict__ row_ptr, int nb, int n) {
    int lane = threadIdx.x;  // 64 threads, nb <= 64
    int v = (lane < nb) ? bsum[lane] : 0;
    int incl = v;
#pragma unroll
    for (int off = 1; off < 64; off <<= 1) {
        int t = __shfl_up(incl, off);
        if (lane >= off) incl += t;
    }
    if (lane < nb) boff[lane] = incl - v;
    if (lane == 63) row_ptr[n] = incl;  // grand total
}

__global__ __launch_bounds__(1024) void add_offsets_kernel(int* __restrict__ row_ptr,
                                                           const int* __restrict__ boff, int n) {
    int i = blockIdx.x * 1024 + threadIdx.x;
    if (i < n) row_ptr[i] += boff[blockIdx.x];
}

__global__ void fill_kernel(const void* __restrict__ edges,
                            const int* __restrict__ row_ptr, int* __restrict__ fill,
                            int* __restrict__ col, int E) {
    int e = blockIdx.x * blockDim.x + threadIdx.x;
    if (e >= E) return;
    int is64 = detect64((const int*)edges);
    int s = edge_at(edges, is64, e);
    int d = edge_at(edges, is64, E + e);
    int pos = row_ptr[d] + atomicAdd(&fill[d], 1);
    col[pos] = s;
}

// ---------------------------------------------------------------------------
// bf16 helpers (RNE)
// ---------------------------------------------------------------------------
__device__ __forceinline__ uint32_t f_to_bf(float f) {
    union { float f; uint32_t u; } v; v.f = f;
    uint32_t u = v.u;
    return (u + 0x7fffu + ((u >> 16) & 1u)) >> 16;
}
__device__ __forceinline__ uint32_t pack_bf2(float a, float b) {
    return f_to_bf(a) | (f_to_bf(b) << 16);
}
__device__ __forceinline__ float2 bf2_to_f2(uint32_t u) {
    union { uint32_t u; float f; } a, b;
    a.u = u << 16; b.u = u & 0xffff0000u;
    float2 r; r.x = a.f; r.y = b.f; return r;
}

// ---------------------------------------------------------------------------
// y[i][:] = (H[i][:] @ W) * dinv[i].  FIN = 128, W staged in LDS.
// Block = 512 threads; thread computes a 4-node x 4-col microtile.
// FOUT=128: 64 nodes/block, 64 KB LDS -> 2 blocks/CU = 16 waves/CU (50% occ).
// BF=true stores y as packed bf16 (halves gather traffic downstream).
// ---------------------------------------------------------------------------
template <int FOUT, bool BF>
__global__ __launch_bounds__(512) void gemm_scale(const float* __restrict__ H,
                                                  const float* __restrict__ W,
                                                  const float* __restrict__ dinv,
                                                  void* __restrict__ Yv, int n) {
    constexpr int FIN = 128;
    constexpr int COLG = FOUT / 4;     // 4-col groups
    constexpr int ROWG = 512 / COLG;   // row groups
    constexpr int NODES = ROWG * 4;    // nodes per block
    __shared__ float Wlds[FIN * FOUT];
    int tid = threadIdx.x;
    for (int idx = tid * 4; idx < FIN * FOUT; idx += 2048) {
        *(float4*)&Wlds[idx] = *(const float4*)&W[idx];
    }
    __syncthreads();
    int r0 = blockIdx.x * NODES;
    int cx = tid % COLG;
    int ry = tid / COLG;
    int nodes[4];
#pragma unroll
    for (int nn = 0; nn < 4; nn++) {
        int node = r0 + ry * 4 + nn;
        nodes[nn] = (node < n) ? node : (n - 1);  // clamp; store is guarded
    }
    float acc[4][4] = {};
    for (int k = 0; k < FIN; k += 4) {
        float4 b0 = *(const float4*)&Wlds[(k + 0) * FOUT + 4 * cx];
        float4 b1 = *(const float4*)&Wlds[(k + 1) * FOUT + 4 * cx];
        float4 b2 = *(const float4*)&Wlds[(k + 2) * FOUT + 4 * cx];
        float4 b3 = *(const float4*)&Wlds[(k + 3) * FOUT + 4 * cx];
#pragma unroll
        for (int nn = 0; nn < 4; nn++) {
            float4 a = *(const float4*)&H[nodes[nn] * FIN + k];
            acc[nn][0] += a.x * b0.x + a.y * b1.x + a.z * b2.x + a.w * b3.x;
            acc[nn][1] += a.x * b0.y + a.y * b1.y + a.z * b2.y + a.w * b3.y;
            acc[nn][2] += a.x * b0.z + a.y * b1.z + a.z * b2.z + a.w * b3.z;
            acc[nn][3] += a.x * b0.w + a.y * b1.w + a.z * b2.w + a.w * b3.w;
        }
    }
#pragma unroll
    for (int nn = 0; nn < 4; nn++) {
        int node = r0 + ry * 4 + nn;
        if (node < n) {
            float di = dinv[node];
            if (BF) {
                uint32_t lo = pack_bf2(acc[nn][0] * di, acc[nn][1] * di);
                uint32_t hi = pack_bf2(acc[nn][2] * di, acc[nn][3] * di);
                uint2 o; o.x = lo; o.y = hi;
                *(uint2*)((uint16_t*)Yv + (size_t)node * FOUT + 4 * cx) = o;
            } else {
                float4 o;
                o.x = acc[nn][0] * di; o.y = acc[nn][1] * di;
                o.z = acc[nn][2] * di; o.w = acc[nn][3] * di;
                *(float4*)((float*)Yv + (size_t)node * FOUT + 4 * cx) = o;
            }
        }
    }
}

// ---------------------------------------------------------------------------
// out[i] = maybe_relu( dinv[i] * (y[i] + sum_{e: dst=i} y[col[e]]) + bias )
// One wave per node; BF=true gathers packed-bf16 rows (half the bytes).
// 4 independent accumulator chains so gather loads overlap.
// ---------------------------------------------------------------------------
template <int CH, bool RELU, bool BF>
__global__ __launch_bounds__(256) void aggregate_kernel(
    const void* __restrict__ Yv, const int* __restrict__ row_ptr,
    const int* __restrict__ col, const float* __restrict__ dinv,
    const float* __restrict__ bias, float* __restrict__ out, int n) {
    int w = blockIdx.x * 4 + (threadIdx.x >> 6);
    int lane = threadIdx.x & 63;
    if (w >= n) return;
    constexpr int V = CH / 64;  // 2 (128ch) or 1 (64ch)

    auto loadrow = [&](int node) -> float2 {
        if (BF) {
            uint32_t u = *((const uint32_t*)Yv + (size_t)node * (CH / 2) + lane);
            return bf2_to_f2(u);
        } else if (V == 2) {
            return *(const float2*)((const float*)Yv + (size_t)node * CH + lane * 2);
        } else {
            float2 r; r.x = ((const float*)Yv)[(size_t)node * CH + lane]; r.y = 0.f;
            return r;
        }
    };

    float2 a0 = loadrow(w);  // self-loop term
    float2 a1 = {0.f, 0.f}, a2 = {0.f, 0.f}, a3 = {0.f, 0.f};
    int start = row_ptr[w], end = row_ptr[w + 1];
    for (int base = start; base < end; base += 64) {
        int cnt = min(64, end - base);
        int sv = (base + lane < end) ? col[base + lane] : 0;
        int j = 0;
        for (; j + 4 <= cnt; j += 4) {
            int s0 = __shfl(sv, j + 0);
            int s1 = __shfl(sv, j + 1);
            int s2 = __shfl(sv, j + 2);
            int s3 = __shfl(sv, j + 3);
            float2 v0 = loadrow(s0);
            float2 v1 = loadrow(s1);
            float2 v2 = loadrow(s2);
            float2 v3 = loadrow(s3);
            a0.x += v0.x; a0.y += v0.y;
            a1.x += v1.x; a1.y += v1.y;
            a2.x += v2.x; a2.y += v2.y;
            a3.x += v3.x; a3.y += v3.y;
        }
        for (; j < cnt; j++) {
            int s = __shfl(sv, j);
            float2 v = loadrow(s);
            a0.x += v.x; a0.y += v.y;
        }
    }
    float di = dinv[w];
    if (V == 2) {
        float ox = (a0.x + a1.x + a2.x + a3.x) * di + bias[lane * 2];
        float oy = (a0.y + a1.y + a2.y + a3.y) * di + bias[lane * 2 + 1];
        if (RELU) { ox = fmaxf(ox, 0.f); oy = fmaxf(oy, 0.f); }
        float2 o; o.x = ox; o.y = oy;
        *(float2*)&out[(size_t)w * CH + lane * 2] = o;
    } else {
        float ox = (a0.x + a1.x + a2.x + a3.x) * di + bias[lane];
        if (RELU) ox = fmaxf(ox, 0.f);
        out[(size_t)w * CH + lane] = ox;
    }
}

extern "C" void kernel_launch(void* const* d_in, const int* in_sizes, int n_in,
                              void* d_out, int out_size, void* d_ws, size_t ws_size,
                              hipStream_t stream) {
    const float* x  = (const float*)d_in[0];
    const void*  ei = d_in[1];
    const float* W1 = (const float*)d_in[2];
    const float* b1 = (const float*)d_in[3];
    const float* W2 = (const float*)d_in[4];
    const float* b2 = (const float*)d_in[5];
    const float* W3 = (const float*)d_in[6];
    const float* b3 = (const float*)d_in[7];
    int n = in_sizes[0] / IN_CH;   // 50000
    int E = in_sizes[1] / 2;       // 800000

    // workspace carve (256B-aligned), total ~55 MB
    char* p = (char*)d_ws;
    auto carve = [&](size_t bytes) {
        char* r = p;
        p += (bytes + 255) & ~(size_t)255;
        return r;
    };
    int*   deg     = (int*)carve((size_t)2 * n * 4);  // [0,n)=deg, [n,2n)=fill ctrs
    int*   fill    = deg + n;
    float* dinv    = (float*)carve((size_t)n * 4);
    int*   row_ptr = (int*)carve((size_t)(n + 1) * 4);
    int*   bsum    = (int*)carve(64 * 4);
    int*   boff    = (int*)carve(64 * 4);
    int*   col     = (int*)carve((size_t)E * 4);
    void*  y       = (void*)carve((size_t)n * HID_CH * 4);  // bf16 (L1/2) or f32 (L3)
    float* h       = (float*)carve((size_t)n * HID_CH * 4);

    const int tpb = 256;
    int eb = (E + tpb - 1) / tpb;
    int nb1024 = (n + 1023) / 1024;  // 49 blocks, <= 64

    // ---- CSR + norm build (once per call, reused by all 3 layers) ----
    hipMemsetAsync(deg, 0, (size_t)2 * n * 4, stream);
    count_kernel<<<eb, tpb, 0, stream>>>(ei, deg, E);
    scan_block_kernel<<<nb1024, 1024, 0, stream>>>(deg, row_ptr, bsum, dinv, n);
    scan_totals_kernel<<<1, 64, 0, stream>>>(bsum, boff, row_ptr, nb1024, n);
    add_offsets_kernel<<<nb1024, 1024, 0, stream>>>(row_ptr, boff, n);
    fill_kernel<<<eb, tpb, 0, stream>>>(ei, row_ptr, fill, col, E);

    int gb128 = (n + 63) / 64;    // 64 nodes/block
    int gb64  = (n + 127) / 128;  // 128 nodes/block
    int ab    = (n + 3) / 4;

    // ---- layer 1: y=bf16(x@W1 * dinv) -> h=relu(agg) ----
    gemm_scale<128, true><<<gb128, 512, 0, stream>>>(x, W1, dinv, y, n);
    aggregate_kernel<128, true, true><<<ab, 256, 0, stream>>>(y, row_ptr, col, dinv, b1, h, n);
    // ---- layer 2 ----
    gemm_scale<128, true><<<gb128, 512, 0, stream>>>(h, W2, dinv, y, n);
    aggregate_kernel<128, true, true><<<ab, 256, 0, stream>>>(y, row_ptr, col, dinv, b2, h, n);
    // ---- layer 3 (no relu, 64 ch, fp32 y for final precision) ----
    gemm_scale<64, false><<<gb64, 512, 0, stream>>>(h, W3, dinv, y, n);
    aggregate_kernel<64, false, false><<<ab, 256, 0, stream>>>(y, row_ptr, col, dinv, b3,
                                                               (float*)d_out, n);
}

// Round 3
// 346.182 us; speedup vs baseline: 1.3689x; 1.0461x over previous
//
#include <hip/hip_runtime.h>
#include <cstdint>

#define IN_CH 128
#define HID_CH 128
#define OUT_CH 64

typedef __attribute__((ext_vector_type(8))) short bf8_t;   // 8 bf16 = 4 VGPRs
typedef __attribute__((ext_vector_type(4))) float f4_t;

// ---------------------------------------------------------------------------
// bf16 helpers (RNE)
// ---------------------------------------------------------------------------
__device__ __forceinline__ uint32_t f_to_bf(float f) {
    union { float f; uint32_t u; } v; v.f = f;
    uint32_t u = v.u;
    return (u + 0x7fffu + ((u >> 16) & 1u)) >> 16;
}
__device__ __forceinline__ float bf_to_f(uint32_t h) {
    union { uint32_t u; float f; } v; v.u = h << 16; return v.f;
}
__device__ __forceinline__ float2 bf2_to_f2(uint32_t u) {
    union { uint32_t u; float f; } a, b;
    a.u = u << 16; b.u = u & 0xffff0000u;
    float2 r; r.x = a.f; r.y = b.f; return r;
}

// ---------------------------------------------------------------------------
// int64-vs-int32 edge layout detection (reference uses int64).
// ---------------------------------------------------------------------------
__device__ __forceinline__ int detect64(const int* __restrict__ e32) {
    return (e32[1] | e32[3] | e32[5] | e32[7]) == 0;
}
__device__ __forceinline__ int edge_at(const void* edges, int is64, int idx) {
    if (is64) return (int)((const long long*)edges)[idx];
    return ((const int*)edges)[idx];
}

__global__ void count_kernel(const void* __restrict__ edges, int* __restrict__ deg, int E) {
    int e = blockIdx.x * blockDim.x + threadIdx.x;
    if (e >= E) return;
    int is64 = detect64((const int*)edges);
    int d = edge_at(edges, is64, E + e);
    atomicAdd(&deg[d], 1);
}

// ---- 3-phase parallel exclusive scan of deg -> row_ptr, dinv fused ----
__global__ __launch_bounds__(1024) void scan_block_kernel(
    const int* __restrict__ deg, int* __restrict__ row_ptr,
    int* __restrict__ bsum, float* __restrict__ dinv, int n) {
    __shared__ int wsum[16];
    int tid = threadIdx.x, lane = tid & 63, wid = tid >> 6;
    int i = blockIdx.x * 1024 + tid;
    int v = (i < n) ? deg[i] : 0;
    if (i < n) dinv[i] = rsqrtf((float)(v + 1));  // +1 = self-loop
    int incl = v;
#pragma unroll
    for (int off = 1; off < 64; off <<= 1) {
        int t = __shfl_up(incl, off);
        if (lane >= off) incl += t;
    }
    if (lane == 63) wsum[wid] = incl;
    __syncthreads();
    if (wid == 0) {
        int s = (lane < 16) ? wsum[lane] : 0;
#pragma unroll
        for (int off = 1; off < 16; off <<= 1) {
            int t = __shfl_up(s, off);
            if (lane >= off) s += t;
        }
        if (lane < 16) wsum[lane] = s;
    }
    __syncthreads();
    int woff = (wid > 0) ? wsum[wid - 1] : 0;
    if (i < n) row_ptr[i] = woff + (incl - v);
    if (tid == 1023) bsum[blockIdx.x] = wsum[15];
}

__global__ void scan_totals_kernel(const int* __restrict__ bsum, int* __restrict__ boff,
                                   int* __restrict__ row_ptr, int nb, int n) {
    int lane = threadIdx.x;  // 64 threads, nb <= 64
    int v = (lane < nb) ? bsum[lane] : 0;
    int incl = v;
#pragma unroll
    for (int off = 1; off < 64; off <<= 1) {
        int t = __shfl_up(incl, off);
        if (lane >= off) incl += t;
    }
    if (lane < nb) boff[lane] = incl - v;
    if (lane == 63) row_ptr[n] = incl;
}

__global__ __launch_bounds__(1024) void add_offsets_kernel(int* __restrict__ row_ptr,
                                                           const int* __restrict__ boff, int n) {
    int i = blockIdx.x * 1024 + threadIdx.x;
    if (i < n) row_ptr[i] += boff[blockIdx.x];
}

__global__ void fill_kernel(const void* __restrict__ edges,
                            const int* __restrict__ row_ptr, int* __restrict__ fill,
                            int* __restrict__ col, int E) {
    int e = blockIdx.x * blockDim.x + threadIdx.x;
    if (e >= E) return;
    int is64 = detect64((const int*)edges);
    int s = edge_at(edges, is64, e);
    int d = edge_at(edges, is64, E + e);
    int pos = row_ptr[d] + atomicAdd(&fill[d], 1);
    col[pos] = s;
}

// ---------------------------------------------------------------------------
// x -> (hi, lo) bf16 split, packed pairs for coalesced u32 stores.
// ---------------------------------------------------------------------------
__global__ void x_split_kernel(const float* __restrict__ x, uint16_t* __restrict__ hi,
                               uint16_t* __restrict__ lo, int total2) {
    int i = blockIdx.x * blockDim.x + threadIdx.x;  // one thread per 2 floats
    if (i >= total2) return;
    float2 v = *(const float2*)&x[(size_t)i * 2];
    uint32_t h0 = f_to_bf(v.x), h1 = f_to_bf(v.y);
    uint32_t l0 = f_to_bf(v.x - bf_to_f(h0)), l1 = f_to_bf(v.y - bf_to_f(h1));
    ((uint32_t*)hi)[i] = h0 | (h1 << 16);
    ((uint32_t*)lo)[i] = l0 | (l1 << 16);
}

// ---------------------------------------------------------------------------
// W (128 x FOUT row-major f32) -> MFMA B-operand fragment order, hi/lo bf16.
// idx = ((kc*NT + nt)*64 + lane)*8 + j  maps to  W[kc*32+(lane>>4)*8+j][nt*16+(lane&15)]
// ---------------------------------------------------------------------------
__global__ void w_split_kernel(const float* __restrict__ W, uint16_t* __restrict__ hi,
                               uint16_t* __restrict__ lo, int FOUT) {
    int idx = blockIdx.x * blockDim.x + threadIdx.x;
    if (idx >= 128 * FOUT) return;
    int j = idx & 7;
    int lane = (idx >> 3) & 63;
    int rem = idx >> 9;
    int NT = FOUT >> 4;
    int nt = rem % NT, kc = rem / NT;
    int k = kc * 32 + ((lane >> 4) << 3) + j;
    int c = nt * 16 + (lane & 15);
    float v = W[(size_t)k * FOUT + c];
    uint32_t h = f_to_bf(v);
    uint32_t l = f_to_bf(v - bf_to_f(h));
    hi[idx] = (uint16_t)h;
    lo[idx] = (uint16_t)l;
}

// ---------------------------------------------------------------------------
// MFMA GEMM: Y[i][:] = (A[i][:] @ W) * dinv[i], A = Ahi + Alo (bf16 split),
// fp32-accuracy via 3-term MFMA (hi*hi + hi*lo + lo*hi). K = 128 fixed.
// Block = 256 thr (4 waves), no LDS. Each wave: 16 rows x 32 cols per tile,
// W frags held in registers (NTW*4*2 frags = 64 VGPRs), grid-stride over
// 16-row node tiles.  FOUT=128: wave w takes col-pair w; FOUT=64: col-pair
// w&1, node tiles split across wave pairs.
// ---------------------------------------------------------------------------
template <int FOUT, bool BFOUT>
__global__ __launch_bounds__(256) void gemm_mfma(
    const uint16_t* __restrict__ Ahi, const uint16_t* __restrict__ Alo,
    const uint16_t* __restrict__ Wfhi, const uint16_t* __restrict__ Wflo,
    const float* __restrict__ dinv, void* __restrict__ Yv, int n) {
    constexpr int NT = FOUT / 16;   // total col tiles
    constexpr int NTW = 2;          // col tiles per wave
    int wid = threadIdx.x >> 6;
    int lane = threadIdx.x & 63;
    int cp, tile0, tstride;
    if (FOUT == 128) { cp = wid;     tile0 = blockIdx.x;                  tstride = gridDim.x; }
    else             { cp = wid & 1; tile0 = blockIdx.x * 2 + (wid >> 1); tstride = gridDim.x * 2; }
    int ntiles = (n + 15) >> 4;

    bf8_t wh[NTW][4], wl[NTW][4];
#pragma unroll
    for (int t = 0; t < NTW; t++) {
        int nt = cp * NTW + t;
#pragma unroll
        for (int kc = 0; kc < 4; kc++) {
            size_t base = ((size_t)(kc * NT + nt) * 64 + lane) * 8;
            wh[t][kc] = *(const bf8_t*)&Wfhi[base];
            wl[t][kc] = *(const bf8_t*)&Wflo[base];
        }
    }
    int row_in = lane & 15;
    int koff = (lane >> 4) << 3;
    int colb = lane & 15;
    int rq = (lane >> 4) << 2;

    for (int tile = tile0; tile < ntiles; tile += tstride) {
        int R = tile << 4;
        int arow = R + row_in; if (arow >= n) arow = n - 1;
        const uint16_t* ap_hi = Ahi + (size_t)arow * 128 + koff;
        const uint16_t* ap_lo = Alo + (size_t)arow * 128 + koff;
        bf8_t ah[4], al[4];
#pragma unroll
        for (int kc = 0; kc < 4; kc++) {
            ah[kc] = *(const bf8_t*)(ap_hi + kc * 32);
            al[kc] = *(const bf8_t*)(ap_lo + kc * 32);
        }
        f4_t acc[NTW];
#pragma unroll
        for (int t = 0; t < NTW; t++) acc[t] = (f4_t){0.f, 0.f, 0.f, 0.f};
#pragma unroll
        for (int kc = 0; kc < 4; kc++) {
#pragma unroll
            for (int t = 0; t < NTW; t++) {
                acc[t] = __builtin_amdgcn_mfma_f32_16x16x32_bf16(ah[kc], wh[t][kc], acc[t], 0, 0, 0);
                acc[t] = __builtin_amdgcn_mfma_f32_16x16x32_bf16(ah[kc], wl[t][kc], acc[t], 0, 0, 0);
                acc[t] = __builtin_amdgcn_mfma_f32_16x16x32_bf16(al[kc], wh[t][kc], acc[t], 0, 0, 0);
            }
        }
#pragma unroll
        for (int t = 0; t < NTW; t++) {
            int col = (cp * NTW + t) * 16 + colb;
#pragma unroll
            for (int r = 0; r < 4; r++) {
                int row = R + rq + r;
                if (row < n) {
                    float v = acc[t][r] * dinv[row];
                    if (BFOUT)
                        ((uint16_t*)Yv)[(size_t)row * FOUT + col] = (uint16_t)f_to_bf(v);
                    else
                        ((float*)Yv)[(size_t)row * FOUT + col] = v;
                }
            }
        }
    }
}

// ---------------------------------------------------------------------------
// out[i] = maybe_relu( dinv[i] * (y[i] + sum_{e: dst=i} y[col[e]]) + bias )
// One wave per node; BF_IN gathers packed bf16 rows.  OUTMODE 0: fp32 out,
// OUTMODE 1: hi/lo bf16 split pair (feeds next layer's MFMA GEMM).
// ---------------------------------------------------------------------------
template <int CH, bool RELU, bool BF_IN, int OUTMODE>
__global__ __launch_bounds__(256) void aggregate_kernel(
    const void* __restrict__ Yv, const int* __restrict__ row_ptr,
    const int* __restrict__ col, const float* __restrict__ dinv,
    const float* __restrict__ bias, void* __restrict__ out0,
    void* __restrict__ out1, int n) {
    int w = blockIdx.x * 4 + (threadIdx.x >> 6);
    int lane = threadIdx.x & 63;
    if (w >= n) return;
    constexpr int V = CH / 64;  // 2 (128ch) or 1 (64ch)

    auto loadrow = [&](int node) -> float2 {
        if (BF_IN) {
            uint32_t u = *((const uint32_t*)Yv + (size_t)node * (CH / 2) + lane);
            return bf2_to_f2(u);
        } else if (V == 2) {
            return *(const float2*)((const float*)Yv + (size_t)node * CH + lane * 2);
        } else {
            float2 r; r.x = ((const float*)Yv)[(size_t)node * CH + lane]; r.y = 0.f;
            return r;
        }
    };

    float2 a0 = loadrow(w);  // self-loop term
    float2 a1 = {0.f, 0.f}, a2 = {0.f, 0.f}, a3 = {0.f, 0.f};
    int start = row_ptr[w], end = row_ptr[w + 1];
    for (int base = start; base < end; base += 64) {
        int cnt = min(64, end - base);
        int sv = (base + lane < end) ? col[base + lane] : 0;
        int j = 0;
        for (; j + 4 <= cnt; j += 4) {
            int s0 = __shfl(sv, j + 0);
            int s1 = __shfl(sv, j + 1);
            int s2 = __shfl(sv, j + 2);
            int s3 = __shfl(sv, j + 3);
            float2 v0 = loadrow(s0);
            float2 v1 = loadrow(s1);
            float2 v2 = loadrow(s2);
            float2 v3 = loadrow(s3);
            a0.x += v0.x; a0.y += v0.y;
            a1.x += v1.x; a1.y += v1.y;
            a2.x += v2.x; a2.y += v2.y;
            a3.x += v3.x; a3.y += v3.y;
        }
        for (; j < cnt; j++) {
            int s = __shfl(sv, j);
            float2 v = loadrow(s);
            a0.x += v.x; a0.y += v.y;
        }
    }
    float di = dinv[w];
    if (V == 2) {
        float ox = (a0.x + a1.x + a2.x + a3.x) * di + bias[lane * 2];
        float oy = (a0.y + a1.y + a2.y + a3.y) * di + bias[lane * 2 + 1];
        if (RELU) { ox = fmaxf(ox, 0.f); oy = fmaxf(oy, 0.f); }
        if (OUTMODE == 0) {
            float2 o; o.x = ox; o.y = oy;
            *(float2*)((float*)out0 + (size_t)w * CH + lane * 2) = o;
        } else {
            uint32_t h0 = f_to_bf(ox), h1 = f_to_bf(oy);
            uint32_t l0 = f_to_bf(ox - bf_to_f(h0)), l1 = f_to_bf(oy - bf_to_f(h1));
            ((uint32_t*)out0)[(size_t)w * (CH / 2) + lane] = h0 | (h1 << 16);
            ((uint32_t*)out1)[(size_t)w * (CH / 2) + lane] = l0 | (l1 << 16);
        }
    } else {
        float ox = (a0.x + a1.x + a2.x + a3.x) * di + bias[lane];
        if (RELU) ox = fmaxf(ox, 0.f);
        ((float*)out0)[(size_t)w * CH + lane] = ox;
    }
}

extern "C" void kernel_launch(void* const* d_in, const int* in_sizes, int n_in,
                              void* d_out, int out_size, void* d_ws, size_t ws_size,
                              hipStream_t stream) {
    const float* x  = (const float*)d_in[0];
    const void*  ei = d_in[1];
    const float* W1 = (const float*)d_in[2];
    const float* b1 = (const float*)d_in[3];
    const float* W2 = (const float*)d_in[4];
    const float* b2 = (const float*)d_in[5];
    const float* W3 = (const float*)d_in[6];
    const float* b3 = (const float*)d_in[7];
    int n = in_sizes[0] / IN_CH;   // 50000
    int E = in_sizes[1] / 2;       // 800000

    // workspace carve (256B-aligned), total ~43 MB
    char* p = (char*)d_ws;
    auto carve = [&](size_t bytes) {
        char* r = p;
        p += (bytes + 255) & ~(size_t)255;
        return r;
    };
    int*      deg     = (int*)carve((size_t)2 * n * 4);  // [0,n)=deg, [n,2n)=fill
    int*      fill    = deg + n;
    float*    dinv    = (float*)carve((size_t)n * 4);
    int*      row_ptr = (int*)carve((size_t)(n + 1) * 4);
    int*      bsum    = (int*)carve(64 * 4);
    int*      boff    = (int*)carve(64 * 4);
    int*      col     = (int*)carve((size_t)E * 4);
    uint16_t* ahi     = (uint16_t*)carve((size_t)n * 128 * 2);  // x-hi, then h-hi
    uint16_t* alo     = (uint16_t*)carve((size_t)n * 128 * 2);  // x-lo, then h-lo
    void*     y       = (void*)carve((size_t)n * 128 * 2);      // bf16[128] or f32[64]
    uint16_t* w1h     = (uint16_t*)carve(128 * 128 * 2);
    uint16_t* w1l     = (uint16_t*)carve(128 * 128 * 2);
    uint16_t* w2h     = (uint16_t*)carve(128 * 128 * 2);
    uint16_t* w2l     = (uint16_t*)carve(128 * 128 * 2);
    uint16_t* w3h     = (uint16_t*)carve(128 * 64 * 2);
    uint16_t* w3l     = (uint16_t*)carve(128 * 64 * 2);

    const int tpb = 256;
    int eb = (E + tpb - 1) / tpb;
    int nb1024 = (n + 1023) / 1024;

    // ---- CSR + norm build ----
    hipMemsetAsync(deg, 0, (size_t)2 * n * 4, stream);
    count_kernel<<<eb, tpb, 0, stream>>>(ei, deg, E);
    scan_block_kernel<<<nb1024, 1024, 0, stream>>>(deg, row_ptr, bsum, dinv, n);
    scan_totals_kernel<<<1, 64, 0, stream>>>(bsum, boff, row_ptr, nb1024, n);
    add_offsets_kernel<<<nb1024, 1024, 0, stream>>>(row_ptr, boff, n);
    fill_kernel<<<eb, tpb, 0, stream>>>(ei, row_ptr, fill, col, E);

    // ---- prepass: bf16 hi/lo splits ----
    int total2 = n * 128 / 2;
    x_split_kernel<<<(total2 + tpb - 1) / tpb, tpb, 0, stream>>>(x, ahi, alo, total2);
    w_split_kernel<<<64, tpb, 0, stream>>>(W1, w1h, w1l, 128);
    w_split_kernel<<<64, tpb, 0, stream>>>(W2, w2h, w2l, 128);
    w_split_kernel<<<32, tpb, 0, stream>>>(W3, w3h, w3l, 64);

    int gb = 782;               // 16-row tiles: 3125; 782*4 >= 3125
    int ab = (n + 3) / 4;

    // ---- layer 1 ----
    gemm_mfma<128, true><<<gb, 256, 0, stream>>>(ahi, alo, w1h, w1l, dinv, y, n);
    aggregate_kernel<128, true, true, 1><<<ab, 256, 0, stream>>>(y, row_ptr, col, dinv,
                                                                 b1, ahi, alo, n);
    // ---- layer 2 ----
    gemm_mfma<128, true><<<gb, 256, 0, stream>>>(ahi, alo, w2h, w2l, dinv, y, n);
    aggregate_kernel<128, true, true, 1><<<ab, 256, 0, stream>>>(y, row_ptr, col, dinv,
                                                                 b2, ahi, alo, n);
    // ---- layer 3 (64 ch, fp32 y, no relu) ----
    gemm_mfma<64, false><<<gb, 256, 0, stream>>>(ahi, alo, w3h, w3l, dinv, y, n);
    aggregate_kernel<64, false, false, 0><<<ab, 256, 0, stream>>>(y, row_ptr, col, dinv,
                                                                  b3, d_out, nullptr, n);
}